// Round 13
// baseline (513.421 us; speedup 1.0000x reference)
//
#include <hip/hip_runtime.h>
#include <math.h>

#define KBINS 8192
#define DDIM  16384      // 2*K
#define HID   2048
#define LASTROW 16384    // the t row of W1 (row index D)

#define C1 8             // rows per mv1 chunk
#define NCH1 2048        // 16384/8 -> 8 blocks/CU
#define C2 8             // rows per mv2 chunk
#define NCH2 256         // 2048/8; grid (8, 256) -> 8 blocks/CU

// Diagnostic reps (idempotent; output identical). Duration-matched bands:
// mv1 x12 ~= cdf x7 so BOTH appear in the top-5 dispatch table.
#define REPS_MV1 12
#define REPS_CDF 7

static constexpr float SQRT2_F  = 1.4142135623730951f;
static constexpr float INVSQ2PI = 0.3989422804014327f;   // 1/sqrt(2*pi)

// Opaque zero: defeats cross-rep CSE / dead-store elimination.
__device__ __forceinline__ int opaque_zero() {
    int z;
    asm volatile("v_mov_b32 %0, 0" : "=v"(z));
    return z;
}

// Branch-free erf approximation (A&S 7.1.26), |err| < 1.5e-7.
__device__ __forceinline__ float fast_erff(float x) {
    float ax = fabsf(x);
    float t  = 1.0f / fmaf(0.3275911f, ax, 1.0f);
    float p  = t * (0.254829592f +
               t * (-0.284496736f +
               t * (1.421413741f +
               t * (-1.453152027f +
               t * 1.061405429f))));
    float r = 1.0f - p * __expf(-ax * ax);
    return copysignf(r, x);
}

// ---- K1: mv1 partials. grid 2048, block 256. x12 reps for counters. ----
__global__ void __launch_bounds__(256)
mv1_partial(const float* __restrict__ mu, const float* __restrict__ W1,
            float* __restrict__ part1) {
    __shared__ float a_s[C1];
    int r0 = blockIdx.x * C1;
    if (threadIdx.x < C1) a_s[threadIdx.x] = mu[r0 + threadIdx.x];
    __syncthreads();
    int c0 = threadIdx.x * 4;
#pragma unroll 1
    for (int rep = 0; rep < REPS_MV1; ++rep) {
        int lz = opaque_zero();
        const float* wp = W1 + (size_t)r0 * HID + lz;
        float4 acc0 = {0.f, 0.f, 0.f, 0.f};
        float4 acc1 = {0.f, 0.f, 0.f, 0.f};
#pragma unroll
        for (int k = 0; k < C1; ++k) {
            float a = a_s[k];
            const float4 w0 = *reinterpret_cast<const float4*>(wp + (size_t)k * HID + c0);
            const float4 w1 = *reinterpret_cast<const float4*>(wp + (size_t)k * HID + c0 + 1024);
            acc0.x += a * w0.x; acc0.y += a * w0.y; acc0.z += a * w0.z; acc0.w += a * w0.w;
            acc1.x += a * w1.x; acc1.y += a * w1.y; acc1.z += a * w1.z; acc1.w += a * w1.w;
        }
        float* pp = part1 + (size_t)blockIdx.x * HID + lz;
        *reinterpret_cast<float4*>(pp + c0)        = acc0;
        *reinterpret_cast<float4*>(pp + c0 + 1024) = acc1;
    }
}

// ---- K2: h reduce. grid 256, block 256. ----
__global__ void __launch_bounds__(256)
h_reduce(const float* __restrict__ part1, const float* __restrict__ b1,
         const float* __restrict__ W1, const float* __restrict__ t,
         float* __restrict__ h) {
    __shared__ float red[32][9];
    int col_l = threadIdx.x & 7;
    int sub   = threadIdx.x >> 3;             // 0..31
    int c0    = blockIdx.x * 8;
    float s = 0.f;
    const float* p = part1 + c0 + col_l;
#pragma unroll 8
    for (int m = 0; m < 64; ++m)
        s += p[(size_t)(sub + (m << 5)) * HID];
    red[sub][col_l] = s;
    __syncthreads();
    if (threadIdx.x < 8) {
        int c = c0 + threadIdx.x;
        float v = b1[c] + t[0] * W1[(size_t)LASTROW * HID + c];
#pragma unroll
        for (int q = 0; q < 32; ++q) v += red[q][threadIdx.x];
        h[c] = (v >= 0.f) ? v : 0.01f * v;
    }
}

// ---- K3: mv2 partials. grid (8, 256), block 256. ----
__global__ void __launch_bounds__(256)
mv2_partial(const float* __restrict__ h, const float* __restrict__ W2,
            float* __restrict__ part2) {
    __shared__ float hs[C2];
    int r0    = blockIdx.y * C2;
    int cbase = blockIdx.x * 2048;
    if (threadIdx.x < C2) hs[threadIdx.x] = h[r0 + threadIdx.x];
    __syncthreads();
    int c0 = cbase + threadIdx.x * 4;
    const float* wp = W2 + (size_t)r0 * DDIM;
    float4 acc0 = {0.f, 0.f, 0.f, 0.f};
    float4 acc1 = {0.f, 0.f, 0.f, 0.f};
#pragma unroll
    for (int k = 0; k < C2; ++k) {
        float a = hs[k];
        const float4 w0 = *reinterpret_cast<const float4*>(wp + (size_t)k * DDIM + c0);
        const float4 w1 = *reinterpret_cast<const float4*>(wp + (size_t)k * DDIM + c0 + 1024);
        acc0.x += a * w0.x; acc0.y += a * w0.y; acc0.z += a * w0.z; acc0.w += a * w0.w;
        acc1.x += a * w1.x; acc1.y += a * w1.y; acc1.z += a * w1.z; acc1.w += a * w1.w;
    }
    float* pp = part2 + (size_t)blockIdx.y * DDIM;
    *reinterpret_cast<float4*>(pp + c0)        = acc0;
    *reinterpret_cast<float4*>(pp + c0 + 1024) = acc1;
}

// ---- K4: mu_x / sigma_x. grid 256, block 256. ----
__global__ void __launch_bounds__(256)
scalars(const float* __restrict__ part2, const float* __restrict__ b2,
        const float* __restrict__ mu, const float* __restrict__ t,
        const float* __restrict__ gamma,
        float* __restrict__ mu_x, float* __restrict__ sigma_x) {
    __shared__ float red0[8][32];
    __shared__ float red1[8][32];
    int col_l = threadIdx.x & 31;
    int sub   = threadIdx.x >> 5;
    int c     = blockIdx.x * 32 + col_l;
    float s0 = 0.f, s1 = 0.f;
    const float* p0 = part2 + c;
    const float* p1 = part2 + c + KBINS;
#pragma unroll 8
    for (int m = 0; m < 32; ++m) {
        size_t off = (size_t)(sub + (m << 3)) * DDIM;
        s0 += p0[off];
        s1 += p1[off];
    }
    red0[sub][col_l] = s0;
    red1[sub][col_l] = s1;
    __syncthreads();
    if (threadIdx.x < 32) {
        int cc = blockIdx.x * 32 + threadIdx.x;
        float v0 = b2[cc];
        float v1 = b2[cc + KBINS];
#pragma unroll
        for (int p = 0; p < 8; ++p) { v0 += red0[p][threadIdx.x]; v1 += red1[p][threadIdx.x]; }
        float g  = gamma[0];
        float pe = 1.0f / (1.0f - g);
        float pm = g - pe;
        bool use_nn = (t[0] >= 1e-10f);
        float mx = powf(mu[cc], pm) * powf(v0, pe);
        float sx = powf(1.0f - g, -0.5f) * expf(0.5f * v1);
        mu_x[cc]    = use_nn ? mx : 0.0f;
        sigma_x[cc] = use_nn ? sx : 1.0f;
    }
}

// ---- K5: cdf rows. grid 4096 x 2 rows. x7 reps for counters. ----
__global__ void __launch_bounds__(256)
cdf_row(const float* __restrict__ mu_x, const float* __restrict__ sigma_x,
        float* __restrict__ out) {
    int tid = threadIdx.x;
#pragma unroll 1
    for (int rep = 0; rep < REPS_CDF; ++rep) {
        int lz = opaque_zero();
        for (int rr = 0; rr < 2; ++rr) {
            int i = blockIdx.x * 2 + rr;
            float m    = mu_x[i + lz];
            float invs = 1.0f / sigma_x[i + lz];
            const float sc = 2.0f / 8191.0f;
            float A    = sc * invs;
            float B    = (-1.0f / 8191.0f - m) * invs;
            float coef = INVSQ2PI * A;
            float* orow = out + (size_t)i * KBINS + lz;
#pragma unroll
            for (int it = 0; it < 8; ++it) {
                int j0 = it * 1024 + tid * 4;
                float4 r;
                if (j0 < 4096) {
                    float u0 = fmaf((float)j0, A, B);
                    float u1 = u0 + A;
                    float u2 = u1 + A;
                    float u3 = u2 + A;
                    r.x = coef * __expf(-0.5f * u0 * u0);
                    r.y = coef * __expf(-0.5f * u1 * u1);
                    r.z = coef * __expf(-0.5f * u2 * u2);
                    r.w = coef * __expf(-0.5f * u3 * u3);
                } else if (j0 == 4096) {
                    float z = (8190.0f / 8191.0f - m) * invs * (1.0f / SQRT2_F);
                    r.x = 0.5f * (1.0f - fast_erff(z));
                    r.y = r.z = r.w = 0.f;
                } else {
                    r.x = r.y = r.z = r.w = 0.f;
                }
                *reinterpret_cast<float4*>(orow + j0) = r;
            }
        }
    }
}

extern "C" void kernel_launch(void* const* d_in, const int* in_sizes, int n_in,
                              void* d_out, int out_size, void* d_ws, size_t ws_size,
                              hipStream_t stream) {
    const float* mu    = (const float*)d_in[0];
    const float* t     = (const float*)d_in[1];
    const float* gamma = (const float*)d_in[2];
    const float* W1    = (const float*)d_in[3];
    const float* b1    = (const float*)d_in[4];
    const float* W2    = (const float*)d_in[5];
    const float* b2    = (const float*)d_in[6];
    float* out = (float*)d_out;

    float* ws    = (float*)d_ws;
    float* part1 = ws;                               // 2048*2048 = 16 MB
    float* h     = part1 + (size_t)NCH1 * HID;       // 2048
    float* part2 = h + HID;                          // 256*16384 = 16 MB
    float* mu_x  = part2 + (size_t)NCH2 * DDIM;      // 8192
    float* sig_x = mu_x + KBINS;                     // 8192

    mv1_partial<<<dim3(NCH1),     dim3(256), 0, stream>>>(mu, W1, part1);
    h_reduce   <<<dim3(256),      dim3(256), 0, stream>>>(part1, b1, W1, t, h);
    mv2_partial<<<dim3(8, NCH2),  dim3(256), 0, stream>>>(h, W2, part2);
    scalars    <<<dim3(256),      dim3(256), 0, stream>>>(part2, b2, mu, t, gamma, mu_x, sig_x);
    cdf_row    <<<dim3(4096),     dim3(256), 0, stream>>>(mu_x, sig_x, out);
}

// Round 14
// 163.636 us; speedup vs baseline: 3.1376x; 3.1376x over previous
//
#include <hip/hip_runtime.h>
#include <math.h>

#define KBINS 8192
#define DDIM  16384      // 2*K
#define HID   2048
#define LASTROW 16384    // the t row of W1 (row index D)

#define C1 8             // rows per mv1 chunk
#define NCH1 2048        // 16384/8 -> 8 blocks/CU
#define NCH2 256         // mv2 chunks (8 rows each)

static constexpr float SQRT2_F  = 1.4142135623730951f;
static constexpr float INVSQ2PI = 0.3989422804014327f;   // 1/sqrt(2*pi)

// Branch-free erf approximation (A&S 7.1.26), |err| < 1.5e-7.
__device__ __forceinline__ float fast_erff(float x) {
    float ax = fabsf(x);
    float t  = 1.0f / fmaf(0.3275911f, ax, 1.0f);
    float p  = t * (0.254829592f +
               t * (-0.284496736f +
               t * (1.421413741f +
               t * (-1.453152027f +
               t * 1.061405429f))));
    float r = 1.0f - p * __expf(-ax * ax);
    return copysignf(r, x);
}

// ---- K1: mv1 partials. grid 2048, block 256. Proven >=6.5 TB/s shape. ----
__global__ void __launch_bounds__(256)
mv1_partial(const float* __restrict__ mu, const float* __restrict__ W1,
            float* __restrict__ part1) {
    __shared__ float a_s[C1];
    int r0 = blockIdx.x * C1;
    if (threadIdx.x < C1) a_s[threadIdx.x] = mu[r0 + threadIdx.x];
    __syncthreads();
    int c0 = threadIdx.x * 4;                 // 0..1020
    const float* wp = W1 + (size_t)r0 * HID;
    float4 acc0 = {0.f, 0.f, 0.f, 0.f};
    float4 acc1 = {0.f, 0.f, 0.f, 0.f};
#pragma unroll
    for (int k = 0; k < C1; ++k) {
        float a = a_s[k];
        const float4 w0 = *reinterpret_cast<const float4*>(wp + (size_t)k * HID + c0);
        const float4 w1 = *reinterpret_cast<const float4*>(wp + (size_t)k * HID + c0 + 1024);
        acc0.x += a * w0.x; acc0.y += a * w0.y; acc0.z += a * w0.z; acc0.w += a * w0.w;
        acc1.x += a * w1.x; acc1.y += a * w1.y; acc1.z += a * w1.z; acc1.w += a * w1.w;
    }
    float* pp = part1 + (size_t)blockIdx.x * HID;
    *reinterpret_cast<float4*>(pp + c0)        = acc0;
    *reinterpret_cast<float4*>(pp + c0 + 1024) = acc1;
}

// ---- K2: fused h-rebuild + mv2 partials. grid (4, 256) = 1024 blocks. ----
// Prologue: rebuild this chunk's 8 h-values from part1 (fixed order ->
// deterministic, identical across the 4 bx blocks; 64 KB, L3-resident).
// Main: stream 8 rows x 4096 cols of W2 (16B/lane float4, 32 loads/thread).
__global__ void __launch_bounds__(256)
mv2h(const float* __restrict__ part1, const float* __restrict__ b1,
     const float* __restrict__ W1, const float* __restrict__ t,
     const float* __restrict__ W2, float* __restrict__ part2) {
    __shared__ float red[32][8];
    __shared__ float hs[8];
    const int tid   = threadIdx.x;
    const int r0    = blockIdx.y * 8;         // h rows of this chunk
    const int cbase = blockIdx.x * 4096;      // col quarter
    {
        int cl  = tid & 7;                    // which h row
        int sub = tid >> 3;                   // 0..31
        float s = 0.f;
        const float* p = part1 + r0 + cl;
#pragma unroll 8
        for (int m = 0; m < 64; ++m)
            s += p[(size_t)(sub + (m << 5)) * HID];
        red[sub][cl] = s;
    }
    __syncthreads();
    if (tid < 8) {
        int r = r0 + tid;
        float v = b1[r] + t[0] * W1[(size_t)LASTROW * HID + r];
#pragma unroll
        for (int q = 0; q < 32; ++q) v += red[q][tid];
        hs[tid] = (v >= 0.f) ? v : 0.01f * v;   // leaky relu
    }
    __syncthreads();
    int c0 = cbase + tid * 4;
    float4 acc[4];
#pragma unroll
    for (int q = 0; q < 4; ++q) acc[q] = {0.f, 0.f, 0.f, 0.f};
    const float* wp = W2 + (size_t)r0 * DDIM + c0;
#pragma unroll 2
    for (int k = 0; k < 8; ++k) {
        float a = hs[k];
        const float* wr = wp + (size_t)k * DDIM;
#pragma unroll
        for (int q = 0; q < 4; ++q) {
            const float4 w = *reinterpret_cast<const float4*>(wr + q * 1024);
            acc[q].x += a * w.x; acc[q].y += a * w.y;
            acc[q].z += a * w.z; acc[q].w += a * w.w;
        }
    }
    float* pp = part2 + (size_t)blockIdx.y * DDIM + c0;
#pragma unroll
    for (int q = 0; q < 4; ++q)
        *reinterpret_cast<float4*>(pp + q * 1024) = acc[q];
}

// ---- K3: fused scalars + cdf. grid 2048 blocks x 4 rows. ----
// Prologue: 8 column-sums of part2 (rows i0..i0+3, mu+sig cols), 8 loads/thread.
// Main: proven 99.5%-of-peak midpoint-rule write loop (4 rows x 32 KB).
__global__ void __launch_bounds__(256)
cdf_fused(const float* __restrict__ part2, const float* __restrict__ b2,
          const float* __restrict__ mu, const float* __restrict__ t,
          const float* __restrict__ gamma, float* __restrict__ out) {
    __shared__ float red[32][8];
    __shared__ float sv[8];
    __shared__ float sA[4], sB[4], sCf[4], sEr[4];
    const int tid = threadIdx.x;
    const int i0  = blockIdx.x * 4;
    {
        int col = tid & 7;                    // 0-3: mu_eps cols, 4-7: ln_sig cols
        int sub = tid >> 3;                   // 0..31
        int gc  = (col < 4) ? (i0 + col) : (KBINS + i0 + col - 4);
        float s = 0.f;
        const float* p = part2 + gc;
#pragma unroll 8
        for (int m = 0; m < 8; ++m)
            s += p[(size_t)(sub + (m << 5)) * DDIM];
        red[sub][col] = s;
    }
    __syncthreads();
    if (tid < 8) {
        int gc = (tid < 4) ? (i0 + tid) : (KBINS + i0 + tid - 4);
        float v = b2[gc];
#pragma unroll
        for (int q = 0; q < 32; ++q) v += red[q][tid];
        sv[tid] = v;
    }
    __syncthreads();
    if (tid < 4) {
        float s0 = sv[tid];
        float s1 = sv[tid + 4];
        float g  = gamma[0];
        float pe = 1.0f / (1.0f - g);
        float pm = g - pe;
        bool use_nn = (t[0] >= 1e-10f);
        float mval = use_nn ? powf(mu[i0 + tid], pm) * powf(s0, pe) : 0.0f;
        float invs = use_nn ? powf(1.0f - g, 0.5f) * expf(-0.5f * s1) : 1.0f;
        const float sc = 2.0f / 8191.0f;
        float A = sc * invs;
        sA[tid]  = A;
        sB[tid]  = (-1.0f / 8191.0f - mval) * invs;
        sCf[tid] = INVSQ2PI * A;
        float z = (8190.0f / 8191.0f - mval) * invs * (1.0f / SQRT2_F);
        sEr[tid] = 0.5f * (1.0f - fast_erff(z));
    }
    __syncthreads();
    for (int rr = 0; rr < 4; ++rr) {
        float A    = sA[rr];
        float B    = sB[rr];
        float coef = sCf[rr];
        float er   = sEr[rr];
        float* orow = out + (size_t)(i0 + rr) * KBINS;
#pragma unroll
        for (int it = 0; it < 8; ++it) {
            int j0 = it * 1024 + tid * 4;
            float4 r;
            if (j0 < 4096) {
                float u0 = fmaf((float)j0, A, B);
                float u1 = u0 + A;
                float u2 = u1 + A;
                float u3 = u2 + A;
                r.x = coef * __expf(-0.5f * u0 * u0);
                r.y = coef * __expf(-0.5f * u1 * u1);
                r.z = coef * __expf(-0.5f * u2 * u2);
                r.w = coef * __expf(-0.5f * u3 * u3);
            } else if (j0 == 4096) {
                r.x = er;
                r.y = r.z = r.w = 0.f;
            } else {
                r.x = r.y = r.z = r.w = 0.f;
            }
            *reinterpret_cast<float4*>(orow + j0) = r;
        }
    }
}

extern "C" void kernel_launch(void* const* d_in, const int* in_sizes, int n_in,
                              void* d_out, int out_size, void* d_ws, size_t ws_size,
                              hipStream_t stream) {
    const float* mu    = (const float*)d_in[0];
    const float* t     = (const float*)d_in[1];
    const float* gamma = (const float*)d_in[2];
    const float* W1    = (const float*)d_in[3];
    const float* b1    = (const float*)d_in[4];
    const float* W2    = (const float*)d_in[5];
    const float* b2    = (const float*)d_in[6];
    float* out = (float*)d_out;

    float* ws    = (float*)d_ws;
    float* part1 = ws;                               // 2048*2048 = 16 MB
    float* part2 = part1 + (size_t)NCH1 * HID;       // 256*16384 = 16 MB

    mv1_partial<<<dim3(NCH1),    dim3(256), 0, stream>>>(mu, W1, part1);
    mv2h       <<<dim3(4, NCH2), dim3(256), 0, stream>>>(part1, b1, W1, t, W2, part2);
    cdf_fused  <<<dim3(2048),    dim3(256), 0, stream>>>(part2, b2, mu, t, gamma, out);
}

// Round 15
// 143.623 us; speedup vs baseline: 3.5748x; 1.1393x over previous
//
#include <hip/hip_runtime.h>
#include <math.h>

#define KBINS 8192
#define DDIM  16384      // 2*K
#define HID   2048
#define LASTROW 16384    // the t row of W1 (row index D)

#define C1 8             // rows per mv1 chunk
#define NCH1 2048        // 16384/8 -> 8 blocks/CU
#define C2 16            // rows per mv2 chunk
#define NCH2 128         // 2048/16; grid (16,128) = 2048 blocks -> 8 blocks/CU

static constexpr float SQRT2_F  = 1.4142135623730951f;
static constexpr float INVSQ2PI = 0.3989422804014327f;   // 1/sqrt(2*pi)

// Branch-free erf approximation (A&S 7.1.26), |err| < 1.5e-7.
__device__ __forceinline__ float fast_erff(float x) {
    float ax = fabsf(x);
    float t  = 1.0f / fmaf(0.3275911f, ax, 1.0f);
    float p  = t * (0.254829592f +
               t * (-0.284496736f +
               t * (1.421413741f +
               t * (-1.453152027f +
               t * 1.061405429f))));
    float r = 1.0f - p * __expf(-ax * ax);
    return copysignf(r, x);
}

// ---- K1: mv1 partials. grid 2048, block 256. 8 blocks/CU. Proven shape. ----
__global__ void __launch_bounds__(256)
mv1_partial(const float* __restrict__ mu, const float* __restrict__ W1,
            float* __restrict__ part1) {
    __shared__ float a_s[C1];
    int r0 = blockIdx.x * C1;
    if (threadIdx.x < C1) a_s[threadIdx.x] = mu[r0 + threadIdx.x];
    __syncthreads();
    int c0 = threadIdx.x * 4;                 // 0..1020
    const float* wp = W1 + (size_t)r0 * HID;
    float4 acc0 = {0.f, 0.f, 0.f, 0.f};
    float4 acc1 = {0.f, 0.f, 0.f, 0.f};
#pragma unroll
    for (int k = 0; k < C1; ++k) {
        float a = a_s[k];
        const float4 w0 = *reinterpret_cast<const float4*>(wp + (size_t)k * HID + c0);
        const float4 w1 = *reinterpret_cast<const float4*>(wp + (size_t)k * HID + c0 + 1024);
        acc0.x += a * w0.x; acc0.y += a * w0.y; acc0.z += a * w0.z; acc0.w += a * w0.w;
        acc1.x += a * w1.x; acc1.y += a * w1.y; acc1.z += a * w1.z; acc1.w += a * w1.w;
    }
    float* pp = part1 + (size_t)blockIdx.x * HID;
    *reinterpret_cast<float4*>(pp + c0)        = acc0;
    *reinterpret_cast<float4*>(pp + c0 + 1024) = acc1;
}

// ---- K2: h = leaky(b1 + t*W1[D] + col-sums of part1). grid 256, coalesced. ----
__global__ void __launch_bounds__(256)
h_reduce(const float* __restrict__ part1, const float* __restrict__ b1,
         const float* __restrict__ W1, const float* __restrict__ t,
         float* __restrict__ h) {
    __shared__ float red[32][9];
    int col_l = threadIdx.x & 7;
    int sub   = threadIdx.x >> 3;             // 0..31
    int c0    = blockIdx.x * 8;
    float s = 0.f;
    const float* p = part1 + c0 + col_l;
#pragma unroll 8
    for (int m = 0; m < 64; ++m)
        s += p[(size_t)(sub + (m << 5)) * HID];
    red[sub][col_l] = s;
    __syncthreads();
    if (threadIdx.x < 8) {
        int c = c0 + threadIdx.x;
        float v = b1[c] + t[0] * W1[(size_t)LASTROW * HID + c];
#pragma unroll
        for (int q = 0; q < 32; ++q) v += red[q][threadIdx.x];
        h[c] = (v >= 0.f) ? v : 0.01f * v;
    }
}

// ---- K3: mv2 partials. grid (16, 128) = 2048 blocks, 8 blocks/CU.
// Block: 16 rows x 1024-col slice; thread: 16 independent float4 loads. ----
__global__ void __launch_bounds__(256)
mv2_partial(const float* __restrict__ h, const float* __restrict__ W2,
            float* __restrict__ part2) {
    __shared__ float hs[C2];
    int r0    = blockIdx.y * C2;
    int cbase = blockIdx.x * 1024;
    if (threadIdx.x < C2) hs[threadIdx.x] = h[r0 + threadIdx.x];
    __syncthreads();
    int c0 = cbase + threadIdx.x * 4;
    const float* wp = W2 + (size_t)r0 * DDIM;
    float4 acc0 = {0.f, 0.f, 0.f, 0.f};
    float4 acc1 = {0.f, 0.f, 0.f, 0.f};
#pragma unroll
    for (int k = 0; k < C2; k += 2) {
        float a0 = hs[k];
        float a1 = hs[k + 1];
        const float4 w0 = *reinterpret_cast<const float4*>(wp + (size_t)k * DDIM + c0);
        const float4 w1 = *reinterpret_cast<const float4*>(wp + (size_t)(k + 1) * DDIM + c0);
        acc0.x += a0 * w0.x; acc0.y += a0 * w0.y; acc0.z += a0 * w0.z; acc0.w += a0 * w0.w;
        acc1.x += a1 * w1.x; acc1.y += a1 * w1.y; acc1.z += a1 * w1.z; acc1.w += a1 * w1.w;
    }
    float4 acc = {acc0.x + acc1.x, acc0.y + acc1.y, acc0.z + acc1.z, acc0.w + acc1.w};
    *reinterpret_cast<float4*>(part2 + (size_t)blockIdx.y * DDIM + c0) = acc;
}

// ---- K4: fused scalars + cdf. grid 2048 blocks x 4 rows. 8 blocks/CU.
// Prologue: 128-deep column sums of part2 (8 cols, ~32KB of lines per block,
// L2-resident 8MB buffer) + per-row scalars. Main: proven 99.5%-peak writes. ----
__global__ void __launch_bounds__(256)
cdf_fused(const float* __restrict__ part2, const float* __restrict__ b2,
          const float* __restrict__ mu, const float* __restrict__ t,
          const float* __restrict__ gamma, float* __restrict__ out) {
    __shared__ float red[32][8];
    __shared__ float sv[8];
    __shared__ float sA[4], sB[4], sCf[4], sEr[4];
    const int tid = threadIdx.x;
    const int i0  = blockIdx.x * 4;
    {
        int col = tid & 7;                    // 0-3: mu_eps cols, 4-7: ln_sig cols
        int sub = tid >> 3;                   // 0..31
        int gc  = (col < 4) ? (i0 + col) : (KBINS + i0 + col - 4);
        float s = 0.f;
        const float* p = part2 + gc;
#pragma unroll
        for (int m = 0; m < 4; ++m)
            s += p[(size_t)(sub + (m << 5)) * DDIM];
        red[sub][col] = s;
    }
    __syncthreads();
    if (tid < 8) {
        int gc = (tid < 4) ? (i0 + tid) : (KBINS + i0 + tid - 4);
        float v = b2[gc];
#pragma unroll
        for (int q = 0; q < 32; ++q) v += red[q][tid];
        sv[tid] = v;
    }
    __syncthreads();
    if (tid < 4) {
        float s0 = sv[tid];
        float s1 = sv[tid + 4];
        float g  = gamma[0];
        float pe = 1.0f / (1.0f - g);
        float pm = g - pe;
        bool use_nn = (t[0] >= 1e-10f);
        float mval = use_nn ? powf(mu[i0 + tid], pm) * powf(s0, pe) : 0.0f;
        float invs = use_nn ? powf(1.0f - g, 0.5f) * expf(-0.5f * s1) : 1.0f;
        const float sc = 2.0f / 8191.0f;
        float A = sc * invs;
        sA[tid]  = A;
        sB[tid]  = (-1.0f / 8191.0f - mval) * invs;
        sCf[tid] = INVSQ2PI * A;
        float z = (8190.0f / 8191.0f - mval) * invs * (1.0f / SQRT2_F);
        sEr[tid] = 0.5f * (1.0f - fast_erff(z));
    }
    __syncthreads();
    for (int rr = 0; rr < 4; ++rr) {
        float A    = sA[rr];
        float B    = sB[rr];
        float coef = sCf[rr];
        float er   = sEr[rr];
        float* orow = out + (size_t)(i0 + rr) * KBINS;
#pragma unroll
        for (int it = 0; it < 8; ++it) {
            int j0 = it * 1024 + tid * 4;
            float4 r;
            if (j0 < 4096) {
                float u0 = fmaf((float)j0, A, B);
                float u1 = u0 + A;
                float u2 = u1 + A;
                float u3 = u2 + A;
                r.x = coef * __expf(-0.5f * u0 * u0);
                r.y = coef * __expf(-0.5f * u1 * u1);
                r.z = coef * __expf(-0.5f * u2 * u2);
                r.w = coef * __expf(-0.5f * u3 * u3);
            } else if (j0 == 4096) {
                r.x = er;
                r.y = r.z = r.w = 0.f;
            } else {
                r.x = r.y = r.z = r.w = 0.f;
            }
            *reinterpret_cast<float4*>(orow + j0) = r;
        }
    }
}

extern "C" void kernel_launch(void* const* d_in, const int* in_sizes, int n_in,
                              void* d_out, int out_size, void* d_ws, size_t ws_size,
                              hipStream_t stream) {
    const float* mu    = (const float*)d_in[0];
    const float* t     = (const float*)d_in[1];
    const float* gamma = (const float*)d_in[2];
    const float* W1    = (const float*)d_in[3];
    const float* b1    = (const float*)d_in[4];
    const float* W2    = (const float*)d_in[5];
    const float* b2    = (const float*)d_in[6];
    float* out = (float*)d_out;

    float* ws    = (float*)d_ws;
    float* part1 = ws;                               // 2048*2048 = 16 MB
    float* h     = part1 + (size_t)NCH1 * HID;       // 2048
    float* part2 = h + HID;                          // 128*16384 = 8 MB

    mv1_partial<<<dim3(NCH1),      dim3(256), 0, stream>>>(mu, W1, part1);
    h_reduce   <<<dim3(256),       dim3(256), 0, stream>>>(part1, b1, W1, t, h);
    mv2_partial<<<dim3(16, NCH2),  dim3(256), 0, stream>>>(h, W2, part2);
    cdf_fused  <<<dim3(2048),      dim3(256), 0, stream>>>(part2, b2, mu, t, gamma, out);
}